// Round 5
// baseline (284077.856 us; speedup 1.0000x reference)
//
#include <hip/hip_runtime.h>

// LSTMRecursiveModel: B=16, L=96, H=256, NL=2, O=32. 3168 sequential steps.
// Persistent kernel, 1 grid barrier/step, software-pipelined:
// phase p computes L0(step p) || L1(step p-1).
//
// Round 5: SINGLE-XCD worker set. Rounds 2-4 proved any cross-XCD coherence
// per phase costs 10-20us (serialized RMW barrier / threadfence wbl2+inv /
// agent-atomic data all serialize at the IF$ coherence point). Fix: launch
// 256 plain WGs, each reads HW_REG_XCC_ID, claims a slot on its XCD; first
// XCD to collect 32 WGs becomes home (pigeonhole: guaranteed), rest exit.
// 82944B dynamic LDS forces 1 WG/CU so all 256 WGs are resident up front.
// All h/pred/flag exchange via volatile (sc0, L1-bypass, L2-cached) loads/
// stores: same-L2 coherent, no fences, no atomics, broadcast-friendly.
//
// Workers: 32 WGs x 768 thr = 384 waves = 128 L0 + 256 L1 (R4 wave layout).
// Weights stationary in VGPRs (128/lane, 4x batch-group duplication).
// L0 wave wid: cols {2wid,2wid+1} x 4 gates, k=256.  L1 wave (wid-128):
// 1 col x 4 gates, concat k=512 ([h0'(s); h1(s-1)]).
// Lane = (g=lane&3 batch-group, kl=lane>>2 k-slice). 512 FMA/lane,
// shfl_xor k-reduce, activation + double cell state on kl==0 lanes.

#define NWORK 32
#define NLAUNCH 256
#define LASTP 3169   // pred for jp=31 fires at p=3169

__device__ __forceinline__ float sigm(float x) { return 1.0f / (1.0f + expf(-x)); }

// ---- L2-coherent (L1-bypassing) volatile access helpers ----
__device__ __forceinline__ float2 vld2(const float* p) {
  union { unsigned long long u; float2 f; } c;
  c.u = *(const volatile unsigned long long*)p; return c.f;
}
__device__ __forceinline__ void vst2(float* p, float2 f) {
  union { unsigned long long u; float2 f; } c; c.f = f;
  *(volatile unsigned long long*)p = c.u;
}
__device__ __forceinline__ float vld1(const float* p) {
  union { unsigned u; float f; } c;
  c.u = *(const volatile unsigned*)p; return c.f;
}
__device__ __forceinline__ void vst1(float* p, float f) {
  union { unsigned u; float f; } c; c.f = f;
  *(volatile unsigned*)p = c.u;
}

// ws layout (floats):
//   h0buf : [2][16][256] at 0      (double-buffered by step parity)
//   h1buf : [2][16][256] at 8192
//   predbuf: [32][16]    at 16384
//   flags  : 32 uints, 64B-strided, at 17024 (..17536)
//   arr[8] : per-XCD arrival counters at 17600
//   home   : winning XCD id at 17608 (init 0xFFFFFFFF)
__global__ void init_kernel(float* __restrict__ out, float* __restrict__ ws) {
  int i = blockIdx.x * blockDim.x + threadIdx.x;
  if (i < 16 * 96) out[i] = 0.0f;
  for (int j = i; j < 17608; j += gridDim.x * blockDim.x) ws[j] = 0.0f;
  if (i == 0) ((unsigned*)ws)[17608] = 0xFFFFFFFFu;
}

extern "C" __global__ __launch_bounds__(768, 3) void lstm_coop(
    const float* __restrict__ x_enc,
    const float* __restrict__ Wih0, const float* __restrict__ Whh0,
    const float* __restrict__ bih0, const float* __restrict__ bhh0,
    const float* __restrict__ Wih1, const float* __restrict__ Whh1,
    const float* __restrict__ bih1, const float* __restrict__ bhh1,
    const float* __restrict__ fc_w, const float* __restrict__ fc_b,
    float* __restrict__ out, float* __restrict__ ws) {
  const int tid = threadIdx.x;
  __shared__ int s_rank;

  float* h0buf = ws;
  float* h1buf = ws + 8192;
  float* predbuf = ws + 16384;
  volatile unsigned* flags = (volatile unsigned*)(ws + 17024);
  unsigned* arr = (unsigned*)(ws + 17600);
  unsigned* home = (unsigned*)(ws + 17608);

  // ---- claim a worker slot; workers = first XCD to collect NWORK WGs ----
  if (tid == 0) {
    unsigned xcc;
    asm volatile("s_getreg_b32 %0, hwreg(HW_REG_XCC_ID)" : "=s"(xcc));
    xcc &= 7u;
    unsigned idx = __hip_atomic_fetch_add(&arr[xcc], 1u, __ATOMIC_ACQ_REL,
                                          __HIP_MEMORY_SCOPE_AGENT);
    int rank = -1;
    if (idx < NWORK) {
      if (idx == NWORK - 1) {
        unsigned expv = 0xFFFFFFFFu;
        __hip_atomic_compare_exchange_strong(home, &expv, xcc, __ATOMIC_ACQ_REL,
                                             __ATOMIC_RELAXED, __HIP_MEMORY_SCOPE_AGENT);
      }
      unsigned hv;
      while ((hv = __hip_atomic_load(home, __ATOMIC_RELAXED,
                                     __HIP_MEMORY_SCOPE_AGENT)) == 0xFFFFFFFFu) {}
      if (hv == xcc) rank = (int)idx;
    }
    s_rank = rank;
  }
  __syncthreads();
  const int rank = s_rank;
  if (rank < 0) return;   // whole WG exits (s_rank uniform)

  const int wave = tid >> 6, lane = tid & 63;
  const int g = lane & 3, kl = lane >> 2;   // batch-group (4 b's), k-slice
  const int wid = rank * 12 + wave;         // 0..383
  const bool isL0 = (wid < 128);

  // ---- stationary weights -> VGPRs (once; plain cached loads) ----
  float4 wreg[32];
  float biasv[8], xw[8];
  int c0 = 0, col = 0;
  if (isL0) {
    c0 = wid * 2;
#pragma unroll
    for (int r = 0; r < 8; ++r) {
      int cv = r >> 2, gate = r & 3;
      int grow = gate * 256 + c0 + cv;
      const float* src = Whh0 + grow * 256 + kl * 16;
#pragma unroll
      for (int j = 0; j < 4; ++j) wreg[r * 4 + j] = *(const float4*)(src + j * 4);
      biasv[r] = bih0[grow] + bhh0[grow];
      xw[r] = Wih0[grow];   // Wih0 is (1024,1)
    }
  } else {
    col = wid - 128;
#pragma unroll
    for (int gate = 0; gate < 4; ++gate) {
      int grow = gate * 256 + col;
      const float* src = (kl < 8) ? (Wih1 + grow * 256 + kl * 32)
                                  : (Whh1 + grow * 256 + (kl - 8) * 32);
#pragma unroll
      for (int j = 0; j < 8; ++j) wreg[gate * 8 + j] = *(const float4*)(src + j * 4);
      biasv[gate] = bih1[grow] + bhh1[grow];
      xw[gate] = 0.0f;
    }
#pragma unroll
    for (int r = 4; r < 8; ++r) { biasv[r] = 0.0f; xw[r] = 0.0f; }
  }

  double cs[8];   // L0: cs[cv*4+bb]; L1: cs[bb]. Valid on kl==0 lanes.
#pragma unroll
  for (int i = 0; i < 8; ++i) cs[i] = 0.0;

  for (int p = 0; p <= LASTP; ++p) {
    float* h0prev = h0buf + ((p + 1) & 1) * 4096;   // h0(p-1) / h0'(s=p-1)
    float* h0cur  = h0buf + (p & 1) * 4096;         // h0(p) dest
    float* h1prev = h1buf + (p & 1) * 4096;         // h1(p-2)
    float* h1cur  = h1buf + ((p + 1) & 1) * 4096;   // h1(p-1) dest

    if (isL0) {
      if (p <= 3167) {
        float acc[8][4];
#pragma unroll
        for (int r = 0; r < 8; ++r)
#pragma unroll
          for (int bb = 0; bb < 4; ++bb) acc[r][bb] = 0.0f;
#pragma unroll
        for (int bb = 0; bb < 4; ++bb) {
          int b = g * 4 + bb;
          const float* hp = h0prev + b * 256 + kl * 16;
          float2 hv[8];
#pragma unroll
          for (int j = 0; j < 8; ++j) hv[j] = vld2(hp + j * 2);
#pragma unroll
          for (int r = 0; r < 8; ++r) {
#pragma unroll
            for (int j = 0; j < 4; ++j) {
              float4 wv = wreg[r * 4 + j];
              acc[r][bb] += wv.x * hv[2 * j].x + wv.y * hv[2 * j].y +
                            wv.z * hv[2 * j + 1].x + wv.w * hv[2 * j + 1].y;
            }
          }
        }
#pragma unroll
        for (int m = 4; m <= 32; m <<= 1)
#pragma unroll
          for (int r = 0; r < 8; ++r)
#pragma unroll
            for (int bb = 0; bb < 4; ++bb) acc[r][bb] += __shfl_xor(acc[r][bb], m);

        if (kl == 0) {
#pragma unroll
          for (int bb = 0; bb < 4; ++bb) {
            int b = g * 4 + bb;
            float xv;
            {
              int s = p;
              if (s < 96) {
                xv = x_enc[b * 96 + s];
              } else {
                int sk = s - 96;
                int k = sk / 96;
                int t = sk - k * 96;
                xv = (t < 96 - k) ? x_enc[b * 96 + k + t]
                                  : vld1(predbuf + (t - 96 + k) * 16 + b);
              }
            }
            float hcol[2];
#pragma unroll
            for (int cv = 0; cv < 2; ++cv) {
              float gi = acc[cv * 4 + 0][bb] + xv * xw[cv * 4 + 0] + biasv[cv * 4 + 0];
              float gf = acc[cv * 4 + 1][bb] + xv * xw[cv * 4 + 1] + biasv[cv * 4 + 1];
              float gg = acc[cv * 4 + 2][bb] + xv * xw[cv * 4 + 2] + biasv[cv * 4 + 2];
              float go = acc[cv * 4 + 3][bb] + xv * xw[cv * 4 + 3] + biasv[cv * 4 + 3];
              double cn = (double)sigm(gf) * cs[cv * 4 + bb] + (double)(sigm(gi) * tanhf(gg));
              hcol[cv] = sigm(go) * tanhf((float)cn);
              cs[cv * 4 + bb] = cn;
            }
            vst2(h0cur + b * 256 + c0, make_float2(hcol[0], hcol[1]));
          }
        }
      }
      // ---- prediction: h1(191+96jp) finalized at phase p-1; parity 1 ----
      if (wid == 0 && p >= 193 && ((p - 193) % 96) == 0) {
        int jp = (p - 193) / 96;
        if (jp < 32) {
          int b = lane & 15, q = lane >> 4;
          const float* hsrc = h1buf + 4096 + b * 256 + q * 64;
          const float* fw = fc_w + q * 64;
          float a = 0.0f;
#pragma unroll
          for (int j = 0; j < 32; ++j) {
            float2 hv = vld2(hsrc + j * 2);
            a += hv.x * fw[j * 2] + hv.y * fw[j * 2 + 1];
          }
          a += __shfl_xor(a, 16);
          a += __shfl_xor(a, 32);
          if (q == 0) {
            float pv = a + fc_b[0];
            vst1(predbuf + jp * 16 + b, pv);
            out[b * 96 + jp] = pv;
          }
        }
      }
    } else {
      if (p >= 1 && p <= 3168) {
        float acc[4][4];
#pragma unroll
        for (int r = 0; r < 4; ++r)
#pragma unroll
          for (int bb = 0; bb < 4; ++bb) acc[r][bb] = 0.0f;
#pragma unroll
        for (int bb = 0; bb < 4; ++bb) {
          int b = g * 4 + bb;
          const float* hp = (kl < 8) ? (h0prev + b * 256 + kl * 32)
                                     : (h1prev + b * 256 + kl * 32 - 256);
          float2 hv[16];
#pragma unroll
          for (int j = 0; j < 16; ++j) hv[j] = vld2(hp + j * 2);
#pragma unroll
          for (int r = 0; r < 4; ++r) {
#pragma unroll
            for (int j = 0; j < 8; ++j) {
              float4 wv = wreg[r * 8 + j];
              acc[r][bb] += wv.x * hv[2 * j].x + wv.y * hv[2 * j].y +
                            wv.z * hv[2 * j + 1].x + wv.w * hv[2 * j + 1].y;
            }
          }
        }
#pragma unroll
        for (int m = 4; m <= 32; m <<= 1)
#pragma unroll
          for (int r = 0; r < 4; ++r)
#pragma unroll
            for (int bb = 0; bb < 4; ++bb) acc[r][bb] += __shfl_xor(acc[r][bb], m);

        if (kl == 0) {
#pragma unroll
          for (int bb = 0; bb < 4; ++bb) {
            int b = g * 4 + bb;
            float gi = acc[0][bb] + biasv[0];
            float gf = acc[1][bb] + biasv[1];
            float gg = acc[2][bb] + biasv[2];
            float go = acc[3][bb] + biasv[3];
            double cn = (double)sigm(gf) * cs[bb] + (double)(sigm(gi) * tanhf(gg));
            float hn = sigm(go) * tanhf((float)cn);
            cs[bb] = cn;
            vst1(h1cur + b * 256 + col, hn);
          }
        }
      }
    }

    // ---- same-L2 flag barrier: store own flag, poll all 32 (volatile/sc0).
    // __syncthreads drains each wave's vmcnt before the flag store. ----
    __syncthreads();
    if (tid == 0) flags[rank * 16] = (unsigned)(p + 1);
    if (wave == 0) {
      const bool active = lane < NWORK;
      volatile unsigned* myf = &flags[(active ? lane : 0) * 16];
      const unsigned tgt = (unsigned)(p + 1);
      while (!__all(!active || *myf >= tgt)) {}
    }
    __syncthreads();
  }
}

extern "C" void kernel_launch(void* const* d_in, const int* in_sizes, int n_in,
                              void* d_out, int out_size, void* d_ws, size_t ws_size,
                              hipStream_t stream) {
  const float* x_enc = (const float*)d_in[0];
  const float* Wih0 = (const float*)d_in[4];
  const float* Whh0 = (const float*)d_in[5];
  const float* bih0 = (const float*)d_in[6];
  const float* bhh0 = (const float*)d_in[7];
  const float* Wih1 = (const float*)d_in[8];
  const float* Whh1 = (const float*)d_in[9];
  const float* bih1 = (const float*)d_in[10];
  const float* bhh1 = (const float*)d_in[11];
  const float* fc_w = (const float*)d_in[12];
  const float* fc_b = (const float*)d_in[13];
  float* out = (float*)d_out;
  float* ws = (float*)d_ws;

  hipLaunchKernelGGL(init_kernel, dim3(8), dim3(256), 0, stream, out, ws);

  const int ldsBytes = 82944;   // dummy dynamic LDS: forces 1 WG/CU
  static int attrSet = 0;
  if (!attrSet) {
    (void)hipFuncSetAttribute((const void*)lstm_coop,
                              hipFuncAttributeMaxDynamicSharedMemorySize, ldsBytes);
    attrSet = 1;
  }

  hipLaunchKernelGGL(lstm_coop, dim3(NLAUNCH), dim3(768), ldsBytes, stream,
                     x_enc, Wih0, Whh0, bih0, bhh0, Wih1, Whh1, bih1, bhh1,
                     fc_w, fc_b, out, ws);
}

// Round 7
// 78503.461 us; speedup vs baseline: 3.6187x; 3.6187x over previous
//
#include <hip/hip_runtime.h>

// LSTMRecursiveModel: B=16, L=96, H=256, NL=2, O=32. 3168 sequential steps.
// Single-XCD persistent kernel: 32 WGs x 512 thr, 1 WG/CU (LDS-forced), on the
// first XCD to collect 32 WGs (R5-proven claim). Phase p = L0(step p)||L1(p-1).
//
// Round 7: proven primitives only.
//  - ALL cross-WG data via __hip_atomic_* relaxed/agent (R4-proven correct).
//    Op count slashed: 8 b64 atomic loads/thread stage h0prev+h1prev (32KB)
//    into LDS once per WG; compute reads LDS. x/pred staged as 16 floats.
//  - No inline-asm memory ops (R6's 4-load asm block = likely hang: output/
//    address register overlap -> corrupted address -> fault loop).
//  - 512thr = 8 waves/CU = 2/SIMD -> 256 VGPR budget: 96 pinned weight VGPRs
//    stay truly resident (R5's VGPR=84 proved demotion at tighter budgets).
//  - Wave owns col cc=rank*8+wv in BOTH layers. Lane=(g=lane&1, kl=lane>>1).
//    fold-reduce: 36 shfl/layer (verified: bb = 4k2+2k1+k0 = kl&7).
//  - LDS h layout: chunk stride 18, batch stride 290 -> b64-aligned, ~2-way
//    (free) bank conflicts.

#define NWORK 32
#define NLAUNCH 256
#define LASTP 3169
#define BSTRIDE 290
#define CSTRIDE 18
#define H1OFF 4640      // 16*290
#define XOFF 9280       // x stage base; lds total 9296 floats

typedef float fx4 __attribute__((ext_vector_type(4)));

__device__ __forceinline__ float sigm(float x) { return 1.0f / (1.0f + expf(-x)); }

__device__ __forceinline__ unsigned long long ald64(const float* p) {
  return __hip_atomic_load((const unsigned long long*)p, __ATOMIC_RELAXED,
                           __HIP_MEMORY_SCOPE_AGENT);
}
__device__ __forceinline__ float ald32(const float* p) {
  unsigned u = __hip_atomic_load((const unsigned*)p, __ATOMIC_RELAXED,
                                 __HIP_MEMORY_SCOPE_AGENT);
  union { unsigned u; float f; } c; c.u = u; return c.f;
}
__device__ __forceinline__ void ast32(float* p, float f) {
  union { unsigned u; float f; } c; c.f = f;
  __hip_atomic_store((unsigned*)p, c.u, __ATOMIC_RELAXED, __HIP_MEMORY_SCOPE_AGENT);
}

// ws float layout: h0buf[2][16][256]@0, h1buf@8192, predbuf[32][16]@16384,
// flags(32 u32, 64B-strided)@17024, arr[8]@17600, home@17608
__global__ void init_kernel(float* __restrict__ out, float* __restrict__ ws) {
  int i = blockIdx.x * blockDim.x + threadIdx.x;
  if (i < 16 * 96) out[i] = 0.0f;
  for (int j = i; j < 17608; j += gridDim.x * blockDim.x) ws[j] = 0.0f;
  if (i == 0) ((unsigned*)ws)[17608] = 0xFFFFFFFFu;
}

extern "C" __global__ __launch_bounds__(512, 2) void lstm_x7(
    const float* __restrict__ x_enc,
    const float* __restrict__ Wih0, const float* __restrict__ Whh0,
    const float* __restrict__ bih0, const float* __restrict__ bhh0,
    const float* __restrict__ Wih1, const float* __restrict__ Whh1,
    const float* __restrict__ bih1, const float* __restrict__ bhh1,
    const float* __restrict__ fc_w, const float* __restrict__ fc_b,
    float* __restrict__ out, float* __restrict__ ws) {
  const int tid = threadIdx.x;
  __shared__ int s_rank;
  extern __shared__ float lds[];

  unsigned* flags = (unsigned*)(ws + 17024);
  unsigned* arr = (unsigned*)(ws + 17600);
  unsigned* home = (unsigned*)(ws + 17608);
  float* predbuf = ws + 16384;

  // ---- claim: first XCD to collect 32 WGs wins (R5-proven) ----
  if (tid == 0) {
    unsigned xcc;
    asm volatile("s_getreg_b32 %0, hwreg(HW_REG_XCC_ID)" : "=s"(xcc));
    xcc &= 7u;
    unsigned idx = __hip_atomic_fetch_add(&arr[xcc], 1u, __ATOMIC_ACQ_REL,
                                          __HIP_MEMORY_SCOPE_AGENT);
    int rank = -1;
    if (idx < NWORK) {
      if (idx == NWORK - 1) {
        unsigned expv = 0xFFFFFFFFu;
        __hip_atomic_compare_exchange_strong(home, &expv, xcc, __ATOMIC_ACQ_REL,
                                             __ATOMIC_RELAXED, __HIP_MEMORY_SCOPE_AGENT);
      }
      unsigned hv;
      while ((hv = __hip_atomic_load(home, __ATOMIC_RELAXED,
                                     __HIP_MEMORY_SCOPE_AGENT)) == 0xFFFFFFFFu) {}
      if (hv == xcc) rank = (int)idx;
    }
    s_rank = rank;
  }
  __syncthreads();
  const int rank = s_rank;
  if (rank < 0) return;

  const int wv = tid >> 6, lane = tid & 63;
  const int g = lane & 1, kl = lane >> 1;    // batch-group (8 b), k-slice (32)
  const int bown = g * 8 + (kl & 7);
  const int cc = rank * 8 + wv;              // owned column, both layers

  // ---- stationary weights -> VGPRs, pinned (96 floats/lane) ----
  fx4 W0[2][4], W1[4][4];
  float bias0[4], xw0[4], bias1[4];
#pragma unroll
  for (int q = 0; q < 4; ++q) {
    int row = q * 256 + cc;
    W0[0][q] = *(const fx4*)(Whh0 + row * 256 + kl * 4);
    W0[1][q] = *(const fx4*)(Whh0 + row * 256 + 128 + kl * 4);
    W1[0][q] = *(const fx4*)(Wih1 + row * 256 + kl * 4);
    W1[1][q] = *(const fx4*)(Wih1 + row * 256 + 128 + kl * 4);
    W1[2][q] = *(const fx4*)(Whh1 + row * 256 + kl * 4);
    W1[3][q] = *(const fx4*)(Whh1 + row * 256 + 128 + kl * 4);
    bias0[q] = bih0[row] + bhh0[row];
    xw0[q] = Wih0[row];                      // Wih0 is (1024,1)
    bias1[q] = bih1[row] + bhh1[row];
  }
#pragma unroll
  for (int q = 0; q < 4; ++q) {
    asm volatile("" : "+v"(W0[0][q]), "+v"(W0[1][q]));
    asm volatile("" : "+v"(W1[0][q]), "+v"(W1[1][q]), "+v"(W1[2][q]), "+v"(W1[3][q]));
  }

  const int k0 = kl & 1, k1 = (kl >> 1) & 1, k2 = (kl >> 2) & 1;

  // fold-reduce: a[4][8] (gate,bb) over 32 kl-lanes -> aq[4] for bb=kl&7.
  auto fold = [&](float (&a)[4][8], float (&aq)[4]) {
    float b2[4][4];
#pragma unroll
    for (int q = 0; q < 4; ++q)
#pragma unroll
      for (int u = 0; u < 4; ++u) {
        float snd = k0 ? a[q][2 * u] : a[q][2 * u + 1];
        float rcv = __shfl_xor(snd, 2);
        b2[q][u] = (k0 ? a[q][2 * u + 1] : a[q][2 * u]) + rcv;
      }
    float c2[4][2];
#pragma unroll
    for (int q = 0; q < 4; ++q)
#pragma unroll
      for (int u = 0; u < 2; ++u) {
        float snd = k1 ? b2[q][2 * u] : b2[q][2 * u + 1];
        float rcv = __shfl_xor(snd, 4);
        c2[q][u] = (k1 ? b2[q][2 * u + 1] : b2[q][2 * u]) + rcv;
      }
#pragma unroll
    for (int q = 0; q < 4; ++q) {
      float snd = k2 ? c2[q][0] : c2[q][1];
      float rcv = __shfl_xor(snd, 8);
      aq[q] = (k2 ? c2[q][1] : c2[q][0]) + rcv;
      aq[q] += __shfl_xor(aq[q], 16);
      aq[q] += __shfl_xor(aq[q], 32);
    }
  };

  double cs0 = 0.0, cs1 = 0.0;

  for (int p = 0; p <= LASTP; ++p) {
    const float* h0prev = ws + ((p + 1) & 1) * 4096;
    float* h0cur = ws + (p & 1) * 4096;
    const float* h1prev = ws + 8192 + (p & 1) * 4096;
    float* h1cur = ws + 8192 + ((p + 1) & 1) * 4096;

    // ---- stage h0prev + h1prev -> LDS via 8 b64 agent-atomic loads ----
    unsigned long long sv[8];
#pragma unroll
    for (int m = 0; m < 8; ++m) {
      int i = tid + m * 512;   // 0..4095
      const float* src = (i < 2048) ? (h0prev + 2 * i) : (h1prev + 2 * (i - 2048));
      sv[m] = ald64(src);
    }
    float xs = 0.0f;
    const bool dox = (tid < 16) && (p <= 3167);
    if (dox) {
      int s = p;
      if (s < 96) {
        xs = x_enc[tid * 96 + s];
      } else {
        int sk = s - 96;
        int k = sk / 96;
        int t = sk - k * 96;
        xs = (t < 96 - k) ? x_enc[tid * 96 + k + t]
                          : ald32(predbuf + (t - 96 + k) * 16 + tid);
      }
    }
#pragma unroll
    for (int m = 0; m < 8; ++m) {
      int i = tid + m * 512;
      int ii = (i < 2048) ? i : (i - 2048);
      int b = ii >> 7, r = ii & 127;
      int idx = ((i < 2048) ? 0 : H1OFF) + b * BSTRIDE + (r >> 3) * CSTRIDE + 2 * (r & 7);
      union { unsigned long long u; float2 f; } c; c.u = sv[m];
      *(float2*)&lds[idx] = c.f;
    }
    if (dox) lds[XOFF + tid] = xs;
    __syncthreads();

    const int cbase = (kl >> 2) * CSTRIDE + 4 * (kl & 3);

    // ---- layer 0, step p ----
    if (p <= 3167) {
      float a[4][8];
#pragma unroll
      for (int q = 0; q < 4; ++q)
#pragma unroll
        for (int bb = 0; bb < 8; ++bb) a[q][bb] = 0.0f;
#pragma unroll
      for (int bb = 0; bb < 8; ++bb) {
        const float* hb = lds + (g * 8 + bb) * BSTRIDE;
        float2 x0 = *(const float2*)(hb + cbase);
        float2 x1 = *(const float2*)(hb + cbase + 2);
        float2 x2 = *(const float2*)(hb + 8 * CSTRIDE + cbase);
        float2 x3 = *(const float2*)(hb + 8 * CSTRIDE + cbase + 2);
#pragma unroll
        for (int q = 0; q < 4; ++q) {
          a[q][bb] += W0[0][q][0] * x0.x + W0[0][q][1] * x0.y +
                      W0[0][q][2] * x1.x + W0[0][q][3] * x1.y +
                      W0[1][q][0] * x2.x + W0[1][q][1] * x2.y +
                      W0[1][q][2] * x3.x + W0[1][q][3] * x3.y;
        }
      }
      float aq[4];
      fold(a, aq);
      float xv = lds[XOFF + bown];
      float gI = aq[0] + xv * xw0[0] + bias0[0];
      float gF = aq[1] + xv * xw0[1] + bias0[1];
      float gG = aq[2] + xv * xw0[2] + bias0[2];
      float gO = aq[3] + xv * xw0[3] + bias0[3];
      double cn = (double)sigm(gF) * cs0 + (double)(sigm(gI) * tanhf(gG));
      float hn = sigm(gO) * tanhf((float)cn);
      cs0 = cn;
      if (kl < 8) ast32(h0cur + bown * 256 + cc, hn);
    }

    // ---- layer 1, step p-1 ----
    if (p >= 1 && p <= 3168) {
      float a[4][8];
#pragma unroll
      for (int q = 0; q < 4; ++q)
#pragma unroll
        for (int bb = 0; bb < 8; ++bb) a[q][bb] = 0.0f;
#pragma unroll
      for (int bb = 0; bb < 8; ++bb) {
        const float* hb0 = lds + (g * 8 + bb) * BSTRIDE;
        const float* hb1 = hb0 + H1OFF;
        float2 x0 = *(const float2*)(hb0 + cbase);
        float2 x1 = *(const float2*)(hb0 + cbase + 2);
        float2 x2 = *(const float2*)(hb0 + 8 * CSTRIDE + cbase);
        float2 x3 = *(const float2*)(hb0 + 8 * CSTRIDE + cbase + 2);
        float2 y0 = *(const float2*)(hb1 + cbase);
        float2 y1 = *(const float2*)(hb1 + cbase + 2);
        float2 y2 = *(const float2*)(hb1 + 8 * CSTRIDE + cbase);
        float2 y3 = *(const float2*)(hb1 + 8 * CSTRIDE + cbase + 2);
#pragma unroll
        for (int q = 0; q < 4; ++q) {
          a[q][bb] += W1[0][q][0] * x0.x + W1[0][q][1] * x0.y +
                      W1[0][q][2] * x1.x + W1[0][q][3] * x1.y +
                      W1[1][q][0] * x2.x + W1[1][q][1] * x2.y +
                      W1[1][q][2] * x3.x + W1[1][q][3] * x3.y +
                      W1[2][q][0] * y0.x + W1[2][q][1] * y0.y +
                      W1[2][q][2] * y1.x + W1[2][q][3] * y1.y +
                      W1[3][q][0] * y2.x + W1[3][q][1] * y2.y +
                      W1[3][q][2] * y3.x + W1[3][q][3] * y3.y;
        }
      }
      float aq[4];
      fold(a, aq);
      float gI = aq[0] + bias1[0];
      float gF = aq[1] + bias1[1];
      float gG = aq[2] + bias1[2];
      float gO = aq[3] + bias1[3];
      double cn = (double)sigm(gF) * cs1 + (double)(sigm(gI) * tanhf(gG));
      float hn = sigm(gO) * tanhf((float)cn);
      cs1 = cn;
      if (kl < 8) ast32(h1cur + bown * 256 + cc, hn);
    }

    // ---- prediction: h1(191+96jp) = staged h1s this phase ----
    if (rank == 0 && wv == 0 && p >= 193 && ((p - 193) % 96) == 0) {
      int jp = (p - 193) / 96;
      if (jp < 32) {
        int pb = lane & 15, q4 = lane >> 4;
        float acc = 0.0f;
#pragma unroll
        for (int j = 0; j < 32; ++j) {
          int kk = q4 * 64 + 2 * j;
          float2 hv = *(const float2*)&lds[H1OFF + pb * BSTRIDE +
                                           (kk >> 4) * CSTRIDE + (kk & 15)];
          acc += hv.x * fc_w[kk] + hv.y * fc_w[kk + 1];
        }
        acc += __shfl_xor(acc, 16);
        acc += __shfl_xor(acc, 32);
        if (q4 == 0) {
          float pv = acc + fc_b[0];
          ast32(predbuf + jp * 16 + pb, pv);
          out[pb * 96 + jp] = pv;
        }
      }
    }

    // ---- flag barrier: atomic store + poll-all (R4/R5-proven) ----
    __syncthreads();   // drains all waves' vmem (incl. atomic h stores)
    if (tid == 0) {
      __hip_atomic_store(&flags[rank * 16], (unsigned)(p + 1), __ATOMIC_RELAXED,
                         __HIP_MEMORY_SCOPE_AGENT);
    }
    if (wv == 0) {
      const bool active = lane < NWORK;
      const unsigned* myf = flags + (active ? lane : 0) * 16;
      const unsigned tgt = (unsigned)(p + 1);
      while (!__all(!active ||
                    __hip_atomic_load(myf, __ATOMIC_RELAXED,
                                      __HIP_MEMORY_SCOPE_AGENT) >= tgt)) {
      }
    }
    __syncthreads();
  }
}

extern "C" void kernel_launch(void* const* d_in, const int* in_sizes, int n_in,
                              void* d_out, int out_size, void* d_ws, size_t ws_size,
                              hipStream_t stream) {
  const float* x_enc = (const float*)d_in[0];
  const float* Wih0 = (const float*)d_in[4];
  const float* Whh0 = (const float*)d_in[5];
  const float* bih0 = (const float*)d_in[6];
  const float* bhh0 = (const float*)d_in[7];
  const float* Wih1 = (const float*)d_in[8];
  const float* Whh1 = (const float*)d_in[9];
  const float* bih1 = (const float*)d_in[10];
  const float* bhh1 = (const float*)d_in[11];
  const float* fc_w = (const float*)d_in[12];
  const float* fc_b = (const float*)d_in[13];
  float* out = (float*)d_out;
  float* ws = (float*)d_ws;

  hipLaunchKernelGGL(init_kernel, dim3(8), dim3(256), 0, stream, out, ws);

  const int ldsBytes = 82944;   // ~37KB used; >80KB forces 1 WG/CU residency
  static int attrSet = 0;
  if (!attrSet) {
    (void)hipFuncSetAttribute((const void*)lstm_x7,
                              hipFuncAttributeMaxDynamicSharedMemorySize, ldsBytes);
    attrSet = 1;
  }

  hipLaunchKernelGGL(lstm_x7, dim3(NLAUNCH), dim3(512), ldsBytes, stream,
                     x_enc, Wih0, Whh0, bih0, bhh0, Wih1, Whh1, bih1, bhh1,
                     fc_w, fc_b, out, ws);
}